// Round 1
// baseline (887.099 us; speedup 1.0000x reference)
//
#include <hip/hip_runtime.h>
#include <cstdint>
#include <cstddef>

#define DEVINL __device__ __forceinline__

typedef __attribute__((ext_vector_type(8))) short short8;
typedef __attribute__((ext_vector_type(4))) float f32x4;
typedef unsigned short u16;
typedef unsigned int u32;

// ---------- bf16 helpers (RNE) ----------
DEVINL u16 f2b(float f) {
    u32 u = __float_as_uint(f);
    u32 r = (u + 0x7fffu + ((u >> 16) & 1u)) >> 16;
    return (u16)r;
}
DEVINL float b2f(u16 h) { return __uint_as_float(((u32)h) << 16); }

DEVINL void gl_lds16(const void* g, void* l) {
    __builtin_amdgcn_global_load_lds(
        (const __attribute__((address_space(1))) void*)g,
        (__attribute__((address_space(3))) void*)l, 16, 0, 0);
}

// ---------- constants ----------
// b=8, H=16, DH=64, f=16, n=196, N=3137, dim=1024
// M = 8*3137 = 25096 rows, qkv elems per tensor = 128*3137*64 = 25698304
#define MROWS   25096
#define NTOK    3137
#define QE      25698304
#define LOG2E   1.4426950408889634f

// ---------- fp32 -> bf16 conversion ----------
__global__ __launch_bounds__(256) void cvt_kernel(const float* __restrict__ in,
                                                  u16* __restrict__ out, int n4) {
    int i = blockIdx.x * blockDim.x + threadIdx.x;
    int stride = gridDim.x * blockDim.x;
    for (int j = i; j < n4; j += stride) {
        float4 v = ((const float4*)in)[j];
        u16 o0 = f2b(v.x), o1 = f2b(v.y), o2 = f2b(v.z), o3 = f2b(v.w);
        ushort4 o; o.x = o0; o.y = o1; o.z = o2; o.w = o3;
        ((ushort4*)out)[j] = o;
    }
}

// ---------- 128x128 bf16 MFMA GEMM (A row-major [M][1024], B = [N][1024] i.e. B^T) ----------
// MODE 0: epilogue scatters to q/k/v per-head layout [bh][n][64] bf16
// MODE 1: epilogue adds bias, writes fp32 [M][1024]
template <int MODE>
__global__ __launch_bounds__(256) void gemm128(const u16* __restrict__ A,
                                               const u16* __restrict__ B,
                                               u16* __restrict__ q_out,
                                               u16* __restrict__ k_out,
                                               u16* __restrict__ v_out,
                                               const float* __restrict__ bias,
                                               float* __restrict__ f_out, int M) {
    __shared__ u16 Alds[128 * 64];
    __shared__ u16 Blds[128 * 64];
    const int tid = threadIdx.x, lane = tid & 63, wid = tid >> 6;
    const int m0 = blockIdx.y * 128, n0 = blockIdx.x * 128;
    const int wm = wid >> 1, wn = wid & 1;

    f32x4 acc[4][4];
    const f32x4 zf = {0.f, 0.f, 0.f, 0.f};
#pragma unroll
    for (int i = 0; i < 4; ++i)
#pragma unroll
        for (int j = 0; j < 4; ++j) acc[i][j] = zf;

    const int srow = (lane >> 3);       // 0..7 within chunk
    const int scol = (lane & 7) * 8;    // 0..56

    for (int ks = 0; ks < 16; ++ks) {
        const int k0 = ks * 64;
#pragma unroll
        for (int i = 0; i < 4; ++i) {
            const int c = wid * 4 + i;          // chunk 0..15
            const int row = c * 8 + srow;       // 0..127
            int ar = m0 + row; if (ar > M - 1) ar = M - 1;
            gl_lds16(A + (size_t)ar * 1024 + k0 + scol, Alds + c * 512);
            gl_lds16(B + (size_t)(n0 + row) * 1024 + k0 + scol, Blds + c * 512);
        }
        __syncthreads();
#pragma unroll
        for (int kk = 0; kk < 2; ++kk) {
            short8 av[4], bv[4];
#pragma unroll
            for (int t = 0; t < 4; ++t)
                av[t] = *(const short8*)(Alds + (wm * 64 + t * 16 + (lane & 15)) * 64 +
                                         kk * 32 + ((lane >> 4) << 3));
#pragma unroll
            for (int t = 0; t < 4; ++t)
                bv[t] = *(const short8*)(Blds + (wn * 64 + t * 16 + (lane & 15)) * 64 +
                                         kk * 32 + ((lane >> 4) << 3));
#pragma unroll
            for (int mf = 0; mf < 4; ++mf)
#pragma unroll
                for (int nf = 0; nf < 4; ++nf)
                    acc[mf][nf] = __builtin_amdgcn_mfma_f32_16x16x32_bf16(
                        av[mf], bv[nf], acc[mf][nf], 0, 0, 0);
        }
        __syncthreads();
    }

    // epilogue: C/D layout col=lane&15, row=(lane>>4)*4+reg
#pragma unroll
    for (int mf = 0; mf < 4; ++mf) {
#pragma unroll
        for (int nf = 0; nf < 4; ++nf) {
#pragma unroll
            for (int r = 0; r < 4; ++r) {
                const int gm = m0 + wm * 64 + mf * 16 + ((lane >> 4) << 2) + r;
                if (gm < M) {
                    const int gc = n0 + wn * 64 + nf * 16 + (lane & 15);
                    if (MODE == 0) {
                        const int t = gc >> 10;
                        const int h = (gc >> 6) & 15;
                        const int d = gc & 63;
                        const u32 bb = (u32)gm / 3137u;
                        const u32 nn = (u32)gm - bb * 3137u;
                        u16* dst = (t == 0) ? q_out : (t == 1) ? k_out : v_out;
                        dst[(((size_t)(bb * 16 + h)) * NTOK + nn) * 64 + d] =
                            f2b(acc[mf][nf][r]);
                    } else {
                        f_out[(size_t)gm * 1024 + gc] = acc[mf][nf][r] + bias[gc];
                    }
                }
            }
        }
    }
}

// ---------- cls-token attention: 1 block per bh (128 blocks) ----------
__global__ __launch_bounds__(256) void attn_cls(const u16* __restrict__ qb,
                                                const u16* __restrict__ kb,
                                                const u16* __restrict__ vb,
                                                u16* __restrict__ attnb) {
    const int bh = blockIdx.x;
    const int bb = bh >> 4, h = bh & 15;
    const size_t base = (size_t)bh * NTOK * 64;
    const int tid = threadIdx.x, lane = tid & 63, wid = tid >> 6;

    __shared__ float qs[64];
    __shared__ float sc[NTOK];
    __shared__ float redbuf[8];
    __shared__ float ored[4][64];

    if (tid < 64) qs[tid] = b2f(qb[base + tid]);
    __syncthreads();

    // scores
    for (int j = tid; j < NTOK; j += 256) {
        const u16* kr = kb + base + (size_t)j * 64;
        float acc = 0.f;
#pragma unroll
        for (int c = 0; c < 8; ++c) {
            short8 v8 = *(const short8*)(kr + c * 8);
#pragma unroll
            for (int t = 0; t < 8; ++t) acc += qs[c * 8 + t] * b2f((u16)v8[t]);
        }
        sc[j] = acc * 0.125f;
    }
    __syncthreads();

    // block max
    float mx = -1e30f;
    for (int j = tid; j < NTOK; j += 256) mx = fmaxf(mx, sc[j]);
#pragma unroll
    for (int m = 32; m >= 1; m >>= 1) mx = fmaxf(mx, __shfl_xor(mx, m));
    if (lane == 0) redbuf[wid] = mx;
    __syncthreads();
    mx = fmaxf(fmaxf(redbuf[0], redbuf[1]), fmaxf(redbuf[2], redbuf[3]));

    // exp + block sum
    float sum = 0.f;
    for (int j = tid; j < NTOK; j += 256) {
        float p = exp2f((sc[j] - mx) * LOG2E);
        sc[j] = p;
        sum += p;
    }
#pragma unroll
    for (int m = 32; m >= 1; m >>= 1) sum += __shfl_xor(sum, m);
    if (lane == 0) redbuf[4 + wid] = sum;
    __syncthreads();
    const float tot = redbuf[4] + redbuf[5] + redbuf[6] + redbuf[7];
    const float rinv = 1.0f / tot;

    // PV: thread (g, d)
    const int d = tid & 63, g = tid >> 6;
    float o = 0.f;
    for (int j = g; j < NTOK; j += 4) o += sc[j] * b2f(vb[base + (size_t)j * 64 + d]);
    ored[g][d] = o;
    __syncthreads();
    if (tid < 64) {
        float r = (ored[0][tid] + ored[1][tid] + ored[2][tid] + ored[3][tid]) * rinv;
        attnb[((size_t)bb * NTOK) * 1024 + h * 64 + tid] = f2b(r);
    }
}

// ---------- spatial attention: 1 block per (bh, f) = 2048 blocks ----------
// q: 196 rows (pad to 13 frags = 208), keys: 197 (pad to 224)
__global__ __launch_bounds__(256) void attn_spatial(const u16* __restrict__ qb,
                                                    const u16* __restrict__ kb,
                                                    const u16* __restrict__ vb,
                                                    u16* __restrict__ attnb) {
    const int blk = blockIdx.x;
    const int bh = blk >> 4, fi = blk & 15;
    const int bb = bh >> 4, h = bh & 15;
    const int tid = threadIdx.x, lane = tid & 63, wid = tid >> 6;
    const size_t kvbase = (size_t)bh * NTOK * 64;

    __shared__ u16 Kl[224 * 72];        // K rows padded stride 72
    __shared__ u16 Vt[64 * 232];        // V transposed: Vt[d][key], stride 232
    __shared__ u16 Pl[4 * 16 * 232];    // per-wave P tile, stride 232

    // stage K (rows >=197 zeroed)
    for (int idx = tid; idx < 224 * 8; idx += 256) {
        const int j = idx >> 3, c = idx & 7;
        short8 val = {0, 0, 0, 0, 0, 0, 0, 0};
        if (j < 197) {
            const int n = (j == 0) ? 0 : (1 + fi * 196 + (j - 1));
            val = *(const short8*)(kb + kvbase + (size_t)n * 64 + c * 8);
        }
        *(short8*)(Kl + j * 72 + c * 8) = val;
    }
    // stage V transposed (keys >=197 zeroed)
    for (int idx = tid; idx < 224 * 64; idx += 256) {
        const int j = idx >> 6, d = idx & 63;
        u16 val = 0;
        if (j < 197) {
            const int n = (j == 0) ? 0 : (1 + fi * 196 + (j - 1));
            val = vb[kvbase + (size_t)n * 64 + d];
        }
        Vt[d * 232 + j] = val;
    }
    __syncthreads();

    u16* pl = Pl + wid * 16 * 232;

    for (int mf = wid; mf < 13; mf += 4) {
        // Q fragments straight from global (clamped rows for pad)
        int qr = mf * 16 + (lane & 15);
        if (qr > 195) qr = 195;
        const size_t qoff = kvbase + (size_t)(1 + fi * 196 + qr) * 64 + ((lane >> 4) << 3);
        const short8 a0 = *(const short8*)(qb + qoff);
        const short8 a1 = *(const short8*)(qb + qoff + 32);

        f32x4 s[14];
        const f32x4 zf = {0.f, 0.f, 0.f, 0.f};
#pragma unroll
        for (int nf = 0; nf < 14; ++nf) s[nf] = zf;
#pragma unroll
        for (int nf = 0; nf < 14; ++nf) {
            const u16* kp = Kl + (nf * 16 + (lane & 15)) * 72 + ((lane >> 4) << 3);
            const short8 b0 = *(const short8*)(kp);
            const short8 b1 = *(const short8*)(kp + 32);
            s[nf] = __builtin_amdgcn_mfma_f32_16x16x32_bf16(a0, b0, s[nf], 0, 0, 0);
            s[nf] = __builtin_amdgcn_mfma_f32_16x16x32_bf16(a1, b1, s[nf], 0, 0, 0);
        }

        // in-register softmax (row = 4*(lane>>4)+reg, col = nf*16 + (lane&15))
        float rls[4];
#pragma unroll
        for (int reg = 0; reg < 4; ++reg) {
            float mx = -1e30f;
#pragma unroll
            for (int nf = 0; nf < 14; ++nf) {
                const int col = nf * 16 + (lane & 15);
                float v = s[nf][reg] * 0.125f;
                if (col >= 197) v = -1e30f;
                s[nf][reg] = v;
                mx = fmaxf(mx, v);
            }
            mx = fmaxf(mx, __shfl_xor(mx, 1));
            mx = fmaxf(mx, __shfl_xor(mx, 2));
            mx = fmaxf(mx, __shfl_xor(mx, 4));
            mx = fmaxf(mx, __shfl_xor(mx, 8));
            float sum = 0.f;
#pragma unroll
            for (int nf = 0; nf < 14; ++nf) {
                const float p = exp2f((s[nf][reg] - mx) * LOG2E);
                s[nf][reg] = p;
                sum += p;
            }
            sum += __shfl_xor(sum, 1);
            sum += __shfl_xor(sum, 2);
            sum += __shfl_xor(sum, 4);
            sum += __shfl_xor(sum, 8);
            rls[reg] = 1.0f / sum;
        }

        // write P (bf16) to per-wave LDS tile
#pragma unroll
        for (int nf = 0; nf < 14; ++nf)
#pragma unroll
            for (int reg = 0; reg < 4; ++reg)
                pl[(((lane >> 4) << 2) + reg) * 232 + nf * 16 + (lane & 15)] =
                    f2b(s[nf][reg]);

        // PV
        f32x4 o[4];
#pragma unroll
        for (int i = 0; i < 4; ++i) o[i] = zf;
#pragma unroll
        for (int kk = 0; kk < 7; ++kk) {
            const short8 pa =
                *(const short8*)(pl + (lane & 15) * 232 + kk * 32 + ((lane >> 4) << 3));
#pragma unroll
            for (int nf2 = 0; nf2 < 4; ++nf2) {
                const short8 bvv = *(const short8*)(Vt + (nf2 * 16 + (lane & 15)) * 232 +
                                                    kk * 32 + ((lane >> 4) << 3));
                o[nf2] = __builtin_amdgcn_mfma_f32_16x16x32_bf16(pa, bvv, o[nf2], 0, 0, 0);
            }
        }

        // epilogue
#pragma unroll
        for (int nf2 = 0; nf2 < 4; ++nf2)
#pragma unroll
            for (int reg = 0; reg < 4; ++reg) {
                const int r = mf * 16 + ((lane >> 4) << 2) + reg;
                if (r < 196) {
                    const int d = nf2 * 16 + (lane & 15);
                    const size_t nn = 1 + fi * 196 + r;
                    attnb[((size_t)bb * NTOK + nn) * 1024 + h * 64 + d] =
                        f2b(o[nf2][reg] * rls[reg]);
                }
            }
    }
}

// ---------- launch ----------
extern "C" void kernel_launch(void* const* d_in, const int* in_sizes, int n_in,
                              void* d_out, int out_size, void* d_ws, size_t ws_size,
                              hipStream_t stream) {
    const float* x = (const float*)d_in[0];
    const float* w_qkv = (const float*)d_in[1];
    const float* w_out = (const float*)d_in[2];
    const float* b_out = (const float*)d_in[3];

    const size_t need = ((size_t)QE * 2 + 3145728 + 1048576) * 2;
    if (ws_size < need) {
        hipMemsetAsync(d_out, 0, (size_t)out_size * 4, stream);
        return;
    }

    u16* vb = (u16*)d_ws;
    u16* xab = vb + QE;            // xb for gemm1, then attention output
    u16* wqb = xab + QE;
    u16* wob = wqb + 3145728;
    u16* qb = (u16*)d_out;         // q,k alias d_out (dead before gemm2 writes)
    u16* kb = qb + QE;
    float* outf = (float*)d_out;

    cvt_kernel<<<2048, 256, 0, stream>>>(x, xab, QE / 4);
    cvt_kernel<<<2048, 256, 0, stream>>>(w_qkv, wqb, 3145728 / 4);
    cvt_kernel<<<1024, 256, 0, stream>>>(w_out, wob, 1048576 / 4);

    gemm128<0><<<dim3(24, 197), 256, 0, stream>>>(xab, wqb, qb, kb, vb, nullptr,
                                                  nullptr, MROWS);
    attn_cls<<<128, 256, 0, stream>>>(qb, kb, vb, xab);
    attn_spatial<<<2048, 256, 0, stream>>>(qb, kb, vb, xab);
    gemm128<1><<<dim3(8, 197), 256, 0, stream>>>(xab, wob, nullptr, nullptr, nullptr,
                                                 b_out, outf, MROWS);
}

// Round 2
// 573.316 us; speedup vs baseline: 1.5473x; 1.5473x over previous
//
#include <hip/hip_runtime.h>
#include <cstdint>
#include <cstddef>

#define DEVINL __device__ __forceinline__

typedef __attribute__((ext_vector_type(8))) short short8;
typedef __attribute__((ext_vector_type(4))) float f32x4;
typedef unsigned short u16;
typedef unsigned int u32;

// ---------- bf16 helpers (RNE) ----------
DEVINL u16 f2b(float f) {
    u32 u = __float_as_uint(f);
    u32 r = (u + 0x7fffu + ((u >> 16) & 1u)) >> 16;
    return (u16)r;
}
DEVINL float b2f(u16 h) { return __uint_as_float(((u32)h) << 16); }

DEVINL void gl_lds16(const void* g, void* l) {
    __builtin_amdgcn_global_load_lds(
        (const __attribute__((address_space(1))) void*)g,
        (__attribute__((address_space(3))) void*)l, 16, 0, 0);
}

// ---------- constants ----------
#define MROWS   25096
#define NTOK    3137
#define QE      25698304
#define LOG2E   1.4426950408889634f

// ---------- fp32 -> bf16 conversion ----------
__global__ __launch_bounds__(256) void cvt_kernel(const float* __restrict__ in,
                                                  u16* __restrict__ out, int n4) {
    int i = blockIdx.x * blockDim.x + threadIdx.x;
    int stride = gridDim.x * blockDim.x;
    for (int j = i; j < n4; j += stride) {
        float4 v = ((const float4*)in)[j];
        ushort4 o;
        o.x = f2b(v.x); o.y = f2b(v.y); o.z = f2b(v.z); o.w = f2b(v.w);
        ((ushort4*)out)[j] = o;
    }
}

// ---------- 128x128 bf16 MFMA GEMM, XCD-swizzled ----------
template <int MODE>
__global__ __launch_bounds__(256) void gemm128(const u16* __restrict__ A,
                                               const u16* __restrict__ B,
                                               u16* __restrict__ q_out,
                                               u16* __restrict__ k_out,
                                               u16* __restrict__ v_out,
                                               const float* __restrict__ bias,
                                               float* __restrict__ f_out, int M) {
    __shared__ u16 Alds[128 * 64];
    __shared__ u16 Blds[128 * 64];
    const int tid = threadIdx.x, lane = tid & 63, wid = tid >> 6;

    // bijective XCD swizzle (m204): consecutive logical tiles -> same XCD
    const u32 nwg = gridDim.x * gridDim.y;
    const u32 orig = blockIdx.y * gridDim.x + blockIdx.x;
    const u32 q8 = nwg >> 3, r8 = nwg & 7, xcd = orig & 7, rest = orig >> 3;
    const u32 wg = (xcd < r8 ? xcd * (q8 + 1) : r8 * (q8 + 1) + (xcd - r8) * q8) + rest;
    const int m0 = (int)(wg / gridDim.x) * 128;
    const int n0 = (int)(wg % gridDim.x) * 128;

    const int wm = wid >> 1, wn = wid & 1;

    f32x4 acc[4][4];
    const f32x4 zf = {0.f, 0.f, 0.f, 0.f};
#pragma unroll
    for (int i = 0; i < 4; ++i)
#pragma unroll
        for (int j = 0; j < 4; ++j) acc[i][j] = zf;

    const int srow = (lane >> 3);
    const int scol = (lane & 7) * 8;

    for (int ks = 0; ks < 16; ++ks) {
        const int k0 = ks * 64;
#pragma unroll
        for (int i = 0; i < 4; ++i) {
            const int c = wid * 4 + i;
            const int row = c * 8 + srow;
            int ar = m0 + row; if (ar > M - 1) ar = M - 1;
            gl_lds16(A + (size_t)ar * 1024 + k0 + scol, Alds + c * 512);
            gl_lds16(B + (size_t)(n0 + row) * 1024 + k0 + scol, Blds + c * 512);
        }
        __syncthreads();
#pragma unroll
        for (int kk = 0; kk < 2; ++kk) {
            short8 av[4], bv[4];
#pragma unroll
            for (int t = 0; t < 4; ++t)
                av[t] = *(const short8*)(Alds + (wm * 64 + t * 16 + (lane & 15)) * 64 +
                                         kk * 32 + ((lane >> 4) << 3));
#pragma unroll
            for (int t = 0; t < 4; ++t)
                bv[t] = *(const short8*)(Blds + (wn * 64 + t * 16 + (lane & 15)) * 64 +
                                         kk * 32 + ((lane >> 4) << 3));
#pragma unroll
            for (int mf = 0; mf < 4; ++mf)
#pragma unroll
                for (int nf = 0; nf < 4; ++nf)
                    acc[mf][nf] = __builtin_amdgcn_mfma_f32_16x16x32_bf16(
                        av[mf], bv[nf], acc[mf][nf], 0, 0, 0);
        }
        __syncthreads();
    }

#pragma unroll
    for (int mf = 0; mf < 4; ++mf) {
#pragma unroll
        for (int nf = 0; nf < 4; ++nf) {
#pragma unroll
            for (int r = 0; r < 4; ++r) {
                const int gm = m0 + wm * 64 + mf * 16 + ((lane >> 4) << 2) + r;
                if (gm < M) {
                    const int gc = n0 + wn * 64 + nf * 16 + (lane & 15);
                    if (MODE == 0) {
                        const int t = gc >> 10;
                        const int h = (gc >> 6) & 15;
                        const int d = gc & 63;
                        const u32 bb = (u32)gm / 3137u;
                        const u32 nn = (u32)gm - bb * 3137u;
                        u16* dst = (t == 0) ? q_out : (t == 1) ? k_out : v_out;
                        dst[(((size_t)(bb * 16 + h)) * NTOK + nn) * 64 + d] =
                            f2b(acc[mf][nf][r]);
                    } else {
                        f_out[(size_t)gm * 1024 + gc] = acc[mf][nf][r] + bias[gc];
                    }
                }
            }
        }
    }
}

// ---------- cls attention, split-K flash: part (1024 blocks) + fin (128 blocks) ----------
#define CSZ 393
__global__ __launch_bounds__(256) void attn_cls_part(const u16* __restrict__ qb,
                                                     const u16* __restrict__ kb,
                                                     const u16* __restrict__ vb,
                                                     float* __restrict__ part) {
    const int bid = blockIdx.x;
    const int bh = bid >> 3, c = bid & 7;
    const size_t base = (size_t)bh * NTOK * 64;
    const int tid = threadIdx.x, lane = tid & 63, wid = tid >> 6;
    const int j0 = c * CSZ;
    const int cnt = min(NTOK - j0, CSZ);

    __shared__ float qs[64];
    __shared__ float sc[CSZ];
    __shared__ float redbuf[8];
    __shared__ float ored[4][64];

    if (tid < 64) qs[tid] = b2f(qb[base + tid]);
    __syncthreads();

    for (int j = tid; j < cnt; j += 256) {
        const u16* kr = kb + base + (size_t)(j0 + j) * 64;
        float acc = 0.f;
#pragma unroll
        for (int c2 = 0; c2 < 8; ++c2) {
            short8 v8 = *(const short8*)(kr + c2 * 8);
#pragma unroll
            for (int t = 0; t < 8; ++t) acc += qs[c2 * 8 + t] * b2f((u16)v8[t]);
        }
        sc[j] = acc * 0.125f;
    }
    __syncthreads();

    float mx = -1e30f;
    for (int j = tid; j < cnt; j += 256) mx = fmaxf(mx, sc[j]);
#pragma unroll
    for (int m = 32; m >= 1; m >>= 1) mx = fmaxf(mx, __shfl_xor(mx, m));
    if (lane == 0) redbuf[wid] = mx;
    __syncthreads();
    mx = fmaxf(fmaxf(redbuf[0], redbuf[1]), fmaxf(redbuf[2], redbuf[3]));

    float sum = 0.f;
    for (int j = tid; j < cnt; j += 256) {
        float p = exp2f((sc[j] - mx) * LOG2E);
        sc[j] = p;
        sum += p;
    }
#pragma unroll
    for (int m = 32; m >= 1; m >>= 1) sum += __shfl_xor(sum, m);
    if (lane == 0) redbuf[4 + wid] = sum;
    __syncthreads();
    const float tot = redbuf[4] + redbuf[5] + redbuf[6] + redbuf[7];

    const int d = tid & 63, g = tid >> 6;
    float o = 0.f;
    for (int j = g; j < cnt; j += 4)
        o += sc[j] * b2f(vb[base + (size_t)(j0 + j) * 64 + d]);
    ored[g][d] = o;
    __syncthreads();

    float* pb = part + (size_t)bid * 66;
    if (tid < 64) pb[2 + tid] = ored[0][tid] + ored[1][tid] + ored[2][tid] + ored[3][tid];
    else if (tid == 64) pb[0] = mx;
    else if (tid == 65) pb[1] = tot;
}

__global__ __launch_bounds__(64) void attn_cls_fin(const float* __restrict__ part,
                                                   u16* __restrict__ attnb) {
    const int bh = blockIdx.x, d = threadIdx.x;
    const int bb = bh >> 4, h = bh & 15;
    float m = -1e30f;
#pragma unroll
    for (int c = 0; c < 8; ++c) m = fmaxf(m, part[(size_t)(bh * 8 + c) * 66]);
    float t = 0.f, o = 0.f;
#pragma unroll
    for (int c = 0; c < 8; ++c) {
        const float* pb = part + (size_t)(bh * 8 + c) * 66;
        const float w = exp2f((pb[0] - m) * LOG2E);
        t += w * pb[1];
        o += w * pb[2 + d];
    }
    attnb[(size_t)bb * NTOK * 1024 + h * 64 + d] = f2b(o / t);
}

// ---------- spatial attention: 2048 blocks, 79.7KB LDS -> 2 blocks/CU ----------
__global__ __launch_bounds__(256) void attn_spatial(const u16* __restrict__ qb,
                                                    const u16* __restrict__ kb,
                                                    const u16* __restrict__ vb,
                                                    u16* __restrict__ attnb) {
    const int blk = blockIdx.x;
    const int bh = blk >> 4, fi = blk & 15;
    const int bb = bh >> 4, h = bh & 15;
    const int tid = threadIdx.x, lane = tid & 63, wid = tid >> 6;
    const int hi = lane >> 4, lo = lane & 15;
    const size_t kvbase = (size_t)bh * NTOK * 64;

    __shared__ u16 Kl[197 * 72];      // K rows, stride 72 (2-way max)
    __shared__ u16 Vt[64 * 208];      // V transposed, stride 208
    __shared__ u16 Pl[4 * 16 * 208];  // per-wave P tile; doubles as V row-major Ptmp

    // pass 1: coalesced staging of K rows and V rows (V -> swizzled Ptmp in Pl)
    u16* Ptmp = Pl;
    for (int idx = tid; idx < 197 * 8; idx += 256) {
        const int j = idx >> 3, c = idx & 7;
        const int n = (j == 0) ? 0 : (1 + fi * 196 + (j - 1));
        *(short8*)(Kl + j * 72 + c * 8) =
            *(const short8*)(kb + kvbase + (size_t)n * 64 + c * 8);
        *(short8*)(Ptmp + ((j * 64 + c * 8) ^ ((j & 7) << 3))) =
            *(const short8*)(vb + kvbase + (size_t)n * 64 + c * 8);
    }
    __syncthreads();
    // pass 2: LDS transpose Ptmp -> Vt (reads 8-way swizzle-spread, writes conflict-free)
#pragma unroll
    for (int c = 0; c < 8; ++c) {
        if (tid < 197) {
            short8 v8 = *(const short8*)(Ptmp + ((tid * 64 + c * 8) ^ ((tid & 7) << 3)));
#pragma unroll
            for (int t = 0; t < 8; ++t) Vt[(c * 8 + t) * 208 + tid] = (u16)v8[t];
        }
    }
    // zero-fill pad cols 197..207 (avoid NaN garbage under P=0)
    for (int idx = tid; idx < 64 * 11; idx += 256)
        Vt[(idx / 11) * 208 + 197 + (idx % 11)] = 0;
    __syncthreads();

    u16* pl = Pl + wid * 16 * 208;
    const short8 z8 = {0, 0, 0, 0, 0, 0, 0, 0};
    const f32x4 zf = {0.f, 0.f, 0.f, 0.f};

    for (int mf = wid; mf < 13; mf += 4) {
        int qr = mf * 16 + lo; if (qr > 195) qr = 195;
        const u16* qp = qb + kvbase + (size_t)(1 + fi * 196 + qr) * 64 + hi * 8;
        const short8 a0 = *(const short8*)(qp);
        const short8 a1 = *(const short8*)(qp + 32);

        f32x4 s[13];
#pragma unroll
        for (int nf = 0; nf < 13; ++nf) s[nf] = zf;
#pragma unroll
        for (int nf = 0; nf < 13; ++nf) {
            int kr = nf * 16 + lo; if (kr > 196) kr = 196;
            const u16* kp = Kl + kr * 72 + hi * 8;
            const short8 b0 = *(const short8*)(kp);
            const short8 b1 = *(const short8*)(kp + 32);
            s[nf] = __builtin_amdgcn_mfma_f32_16x16x32_bf16(a0, b0, s[nf], 0, 0, 0);
            s[nf] = __builtin_amdgcn_mfma_f32_16x16x32_bf16(a1, b1, s[nf], 0, 0, 0);
        }

        float rls[4];
#pragma unroll
        for (int reg = 0; reg < 4; ++reg) {
            float mx = -1e30f;
#pragma unroll
            for (int nf = 0; nf < 13; ++nf) {
                const int col = nf * 16 + lo;
                float v = s[nf][reg] * 0.125f;
                if (col >= 197) v = -1e30f;
                s[nf][reg] = v;
                mx = fmaxf(mx, v);
            }
            mx = fmaxf(mx, __shfl_xor(mx, 1));
            mx = fmaxf(mx, __shfl_xor(mx, 2));
            mx = fmaxf(mx, __shfl_xor(mx, 4));
            mx = fmaxf(mx, __shfl_xor(mx, 8));
            float sum = 0.f;
#pragma unroll
            for (int nf = 0; nf < 13; ++nf) {
                const float p = exp2f((s[nf][reg] - mx) * LOG2E);
                s[nf][reg] = p;
                sum += p;
            }
            sum += __shfl_xor(sum, 1);
            sum += __shfl_xor(sum, 2);
            sum += __shfl_xor(sum, 4);
            sum += __shfl_xor(sum, 8);
            rls[reg] = 1.0f / sum;
        }

#pragma unroll
        for (int nf = 0; nf < 13; ++nf)
#pragma unroll
            for (int reg = 0; reg < 4; ++reg)
                pl[(hi * 4 + reg) * 208 + nf * 16 + lo] = f2b(s[nf][reg]);

        f32x4 o[4];
#pragma unroll
        for (int i = 0; i < 4; ++i) o[i] = zf;
#pragma unroll
        for (int kk = 0; kk < 6; ++kk) {
            const short8 pa = *(const short8*)(pl + lo * 208 + kk * 32 + hi * 8);
#pragma unroll
            for (int nf2 = 0; nf2 < 4; ++nf2) {
                const short8 bvv =
                    *(const short8*)(Vt + (nf2 * 16 + lo) * 208 + kk * 32 + hi * 8);
                o[nf2] = __builtin_amdgcn_mfma_f32_16x16x32_bf16(pa, bvv, o[nf2], 0, 0, 0);
            }
        }
        {   // tail: keys 192..207 real (hi<2), hi>=2 lanes contribute zeros
            const u16* pap = pl + lo * 208 + 192 + (hi < 2 ? hi * 8 : 0);
            short8 pa = *(const short8*)pap;
            if (hi >= 2) pa = z8;
#pragma unroll
            for (int nf2 = 0; nf2 < 4; ++nf2) {
                const u16* bvp = Vt + (nf2 * 16 + lo) * 208 + 192 + (hi < 2 ? hi * 8 : 0);
                short8 bvv = *(const short8*)bvp;
                if (hi >= 2) bvv = z8;
                o[nf2] = __builtin_amdgcn_mfma_f32_16x16x32_bf16(pa, bvv, o[nf2], 0, 0, 0);
            }
        }

#pragma unroll
        for (int nf2 = 0; nf2 < 4; ++nf2)
#pragma unroll
            for (int reg = 0; reg < 4; ++reg) {
                const int r = mf * 16 + hi * 4 + reg;
                if (r < 196) {
                    const int d = nf2 * 16 + lo;
                    const size_t nn = 1 + fi * 196 + r;
                    attnb[((size_t)bb * NTOK + nn) * 1024 + h * 64 + d] =
                        f2b(o[nf2][reg] * rls[reg]);
                }
            }
    }
}

// ---------- launch ----------
extern "C" void kernel_launch(void* const* d_in, const int* in_sizes, int n_in,
                              void* d_out, int out_size, void* d_ws, size_t ws_size,
                              hipStream_t stream) {
    const float* x = (const float*)d_in[0];
    const float* w_qkv = (const float*)d_in[1];
    const float* w_out = (const float*)d_in[2];
    const float* b_out = (const float*)d_in[3];

    const size_t need = ((size_t)QE * 2 + 3145728 + 1048576) * 2;
    if (ws_size < need) {
        hipMemsetAsync(d_out, 0, (size_t)out_size * 4, stream);
        return;
    }

    u16* vb = (u16*)d_ws;
    u16* xab = vb + QE;            // x bf16 for gemm1, then attention output
    u16* wqb = xab + QE;           // w_qkv bf16; dead after gemm1 -> reused for cls partials
    u16* wob = wqb + 3145728;
    u16* qb = (u16*)d_out;         // q,k alias d_out (dead before gemm2 writes)
    u16* kb = qb + QE;
    float* outf = (float*)d_out;
    float* clsp = (float*)wqb;     // 1024*66 floats, reuses dead w_qkv bf16 region

    cvt_kernel<<<2048, 256, 0, stream>>>(x, xab, QE / 4);
    cvt_kernel<<<2048, 256, 0, stream>>>(w_qkv, wqb, 3145728 / 4);
    cvt_kernel<<<1024, 256, 0, stream>>>(w_out, wob, 1048576 / 4);

    gemm128<0><<<dim3(24, 197), 256, 0, stream>>>(xab, wqb, qb, kb, vb, nullptr,
                                                  nullptr, MROWS);
    attn_cls_part<<<1024, 256, 0, stream>>>(qb, kb, vb, clsp);
    attn_cls_fin<<<128, 64, 0, stream>>>(clsp, xab);
    attn_spatial<<<2048, 256, 0, stream>>>(qb, kb, vb, xab);
    gemm128<1><<<dim3(8, 197), 256, 0, stream>>>(xab, wob, nullptr, nullptr, nullptr,
                                                 b_out, outf, MROWS);
}

// Round 3
// 469.981 us; speedup vs baseline: 1.8875x; 1.2199x over previous
//
#include <hip/hip_runtime.h>
#include <cstdint>
#include <cstddef>

#define DEVINL __device__ __forceinline__

typedef __attribute__((ext_vector_type(8))) short short8;
typedef __attribute__((ext_vector_type(4))) float f32x4;
typedef unsigned short u16;
typedef unsigned int u32;

// ---------- bf16 helpers (RNE) ----------
DEVINL u16 f2b(float f) {
    u32 u = __float_as_uint(f);
    u32 r = (u + 0x7fffu + ((u >> 16) & 1u)) >> 16;
    return (u16)r;
}
DEVINL float b2f(u16 h) { return __uint_as_float(((u32)h) << 16); }

DEVINL void gl_lds16(const void* g, void* l) {
    __builtin_amdgcn_global_load_lds(
        (const __attribute__((address_space(1))) void*)g,
        (__attribute__((address_space(3))) void*)l, 16, 0, 0);
}

// ---------- constants ----------
#define MROWS   25096
#define NTOK    3137
#define QE      25698304
#define LOG2E   1.4426950408889634f

// ---------- fp32 -> bf16 conversion ----------
__global__ __launch_bounds__(256) void cvt_kernel(const float* __restrict__ in,
                                                  u16* __restrict__ out, int n4) {
    int i = blockIdx.x * blockDim.x + threadIdx.x;
    int stride = gridDim.x * blockDim.x;
    for (int j = i; j < n4; j += stride) {
        float4 v = ((const float4*)in)[j];
        ushort4 o;
        o.x = f2b(v.x); o.y = f2b(v.y); o.z = f2b(v.z); o.w = f2b(v.w);
        ((ushort4*)out)[j] = o;
    }
}

// ================= 256x256 8-phase bf16 MFMA GEMM =================
// A row-major [M][1024], B = [N][1024] (B^T input). K = 1024, NT = 16 K-tiles.
// 512 threads = 8 waves (2 M x 4 N). LDS: 2 bufs x (A[2][256][32] + B[2][256][32])
// bf16 (K-half-major; 64-B row stride => conflict-free ds_read_b128).
// Schedule per K-tile T (4 phases):
//  p1: read Ak0(m0-3)+Bk0, stage T+1 Ak0 ; MFMA m0-3 kk0
//  p2: read Ak0(m4-7),     stage T+1 Bk0 ; MFMA m4-7 kk0 ; vmcnt(4) [proves T k1]
//  p3: read Ak1(m0-3)+Bk1, stage T+1 Ak1 ; MFMA m0-3 kk1
//  p4: read Ak1(m4-7),     stage T+1 Bk1 ; MFMA m4-7 kk1 ; vmcnt(4) [proves T+1 k0]
// vmcnt placed BEFORE the phase's closing s_barrier so peers can't read early.
// Never drains to 0 in main loop (tail: vmcnt(0) once at T=NT-1 p2).

#define LDS_BUF 32768   // elems per buffer (A 16384 + B 16384)
#define NTILES  16

template <int MODE>
__global__ __launch_bounds__(512, 2) void gemm256(const u16* __restrict__ A,
                                                  const u16* __restrict__ B,
                                                  u16* __restrict__ q_out,
                                                  u16* __restrict__ k_out,
                                                  u16* __restrict__ v_out,
                                                  const float* __restrict__ bias,
                                                  float* __restrict__ f_out, int M) {
    __shared__ u16 lds[2 * LDS_BUF];   // 128 KiB
    const int tid = threadIdx.x, lane = tid & 63, w = tid >> 6;
    const int Mm1 = M - 1;

    // bijective XCD swizzle (m204)
    const u32 nwg = gridDim.x * gridDim.y;
    const u32 orig = blockIdx.y * gridDim.x + blockIdx.x;
    const u32 q8 = nwg >> 3, r8 = nwg & 7, xcd = orig & 7, rest = orig >> 3;
    const u32 wg = (xcd < r8 ? xcd * (q8 + 1) : r8 * (q8 + 1) + (xcd - r8) * q8) + rest;
    const int m0 = (int)(wg / gridDim.x) * 256;
    const int n0 = (int)(wg % gridDim.x) * 256;

    const int wm = w >> 2, wn = w & 3;

    // staging geometry: chunk c = 2w+j covers 16 rows; lane -> (row = c*16 + (lane>>2), col = (lane&3)*8)
    const int stRow = lane >> 2;
    const int stCol = (lane & 3) * 8;

    // fragment read offsets (elems): row*32 + (lane>>4)*8 within a [256][32] half
    const int rdA = (wm * 128 + (lane & 15)) * 32 + ((lane >> 4) << 3);
    const int rdB = (wn * 64 + (lane & 15)) * 32 + ((lane >> 4) << 3) + 16384;

#define STAGE_A(NB, KK, KT) do {                                              \
    _Pragma("unroll") for (int j_ = 0; j_ < 2; ++j_) {                        \
        const int c_ = (w << 1) | j_;                                         \
        int r_ = m0 + c_ * 16 + stRow; if (r_ > Mm1) r_ = Mm1;                \
        gl_lds16(A + (size_t)r_ * 1024 + (KT) + (KK) * 32 + stCol,            \
                 lds + (NB) + (KK) * 8192 + c_ * 512);                        \
    } } while (0)

#define STAGE_B(NB, KK, KT) do {                                              \
    _Pragma("unroll") for (int j_ = 0; j_ < 2; ++j_) {                        \
        const int c_ = (w << 1) | j_;                                         \
        const int r_ = n0 + c_ * 16 + stRow;                                  \
        gl_lds16(B + (size_t)r_ * 1024 + (KT) + (KK) * 32 + stCol,            \
                 lds + (NB) + 16384 + (KK) * 8192 + c_ * 512);                \
    } } while (0)

#define LDA4(CB, KK, MB) do {                                                 \
    _Pragma("unroll") for (int i_ = 0; i_ < 4; ++i_)                          \
        aF[i_] = *(const short8*)&lds[(CB) + (KK) * 8192 + rdA +              \
                                      ((MB) + i_) * 16 * 32];                 \
    } while (0)

#define LDB4(CB, KK) do {                                                     \
    _Pragma("unroll") for (int i_ = 0; i_ < 4; ++i_)                          \
        bF[i_] = *(const short8*)&lds[(CB) + (KK) * 8192 + rdB +              \
                                      i_ * 16 * 32];                          \
    } while (0)

#define MFMA16(MB) do {                                                       \
    _Pragma("unroll") for (int i_ = 0; i_ < 4; ++i_)                          \
        _Pragma("unroll") for (int n_ = 0; n_ < 4; ++n_)                      \
            acc[(MB) + i_][n_] = __builtin_amdgcn_mfma_f32_16x16x32_bf16(     \
                aF[i_], bF[n_], acc[(MB) + i_][n_], 0, 0, 0);                 \
    } while (0)

#define LGKM0_FENCE() do {                                                    \
    asm volatile("s_waitcnt lgkmcnt(0)" ::: "memory");                        \
    __builtin_amdgcn_sched_barrier(0); } while (0)

    f32x4 acc[8][4];
    const f32x4 zf = {0.f, 0.f, 0.f, 0.f};
#pragma unroll
    for (int i = 0; i < 8; ++i)
#pragma unroll
        for (int j = 0; j < 4; ++j) acc[i][j] = zf;

    // ---- prologue: stage tile 0 fully into buf0, prove k0 halves ----
    STAGE_A(0, 0, 0);
    STAGE_B(0, 0, 0);
    STAGE_A(0, 1, 0);
    STAGE_B(0, 1, 0);
    asm volatile("s_waitcnt vmcnt(4)" ::: "memory");
    __builtin_amdgcn_sched_barrier(0);
    __builtin_amdgcn_s_barrier();

    for (int T = 0; T < NTILES; ++T) {
        const int cb = (T & 1) * LDS_BUF;
        const int nb = ((T + 1) & 1) * LDS_BUF;
        const bool pf = (T < NTILES - 1);
        const int kt1 = (T + 1) * 64;

        short8 aF[4], bF[4];

        // ---- phase 1: kk0, m0-3 ----
        LDA4(cb, 0, 0);
        LDB4(cb, 0);
        if (pf) STAGE_A(nb, 0, kt1);
        __builtin_amdgcn_s_barrier();
        LGKM0_FENCE();
        __builtin_amdgcn_s_setprio(1);
        MFMA16(0);
        __builtin_amdgcn_s_setprio(0);
        __builtin_amdgcn_s_barrier();

        // ---- phase 2: kk0, m4-7 ----
        LDA4(cb, 0, 4);
        if (pf) STAGE_B(nb, 0, kt1);
        __builtin_amdgcn_s_barrier();
        LGKM0_FENCE();
        __builtin_amdgcn_s_setprio(1);
        MFMA16(4);
        __builtin_amdgcn_s_setprio(0);
        if (pf) { asm volatile("s_waitcnt vmcnt(4)" ::: "memory"); }
        else    { asm volatile("s_waitcnt vmcnt(0)" ::: "memory"); }
        __builtin_amdgcn_sched_barrier(0);
        __builtin_amdgcn_s_barrier();

        // ---- phase 3: kk1, m0-3 ----
        LDA4(cb, 1, 0);
        LDB4(cb, 1);
        if (pf) STAGE_A(nb, 1, kt1);
        __builtin_amdgcn_s_barrier();
        LGKM0_FENCE();
        __builtin_amdgcn_s_setprio(1);
        MFMA16(0);
        __builtin_amdgcn_s_setprio(0);
        __builtin_amdgcn_s_barrier();

        // ---- phase 4: kk1, m4-7 ----
        LDA4(cb, 1, 4);
        if (pf) STAGE_B(nb, 1, kt1);
        __builtin_amdgcn_s_barrier();
        LGKM0_FENCE();
        __builtin_amdgcn_s_setprio(1);
        MFMA16(4);
        __builtin_amdgcn_s_setprio(0);
        if (pf) {
            asm volatile("s_waitcnt vmcnt(4)" ::: "memory");
            __builtin_amdgcn_sched_barrier(0);
        }
        __builtin_amdgcn_s_barrier();
    }

    // ---- epilogue: C layout col=lane&15, row=(lane>>4)*4+reg ----
#pragma unroll
    for (int m = 0; m < 8; ++m) {
#pragma unroll
        for (int n = 0; n < 4; ++n) {
#pragma unroll
            for (int r = 0; r < 4; ++r) {
                const int gm = m0 + wm * 128 + m * 16 + ((lane >> 4) << 2) + r;
                if (gm < M) {
                    const int gc = n0 + wn * 64 + n * 16 + (lane & 15);
                    if (MODE == 0) {
                        const int t = gc >> 10;
                        const int h = (gc >> 6) & 15;
                        const int d = gc & 63;
                        const u32 bb = (u32)gm / 3137u;
                        const u32 nn = (u32)gm - bb * 3137u;
                        u16* dst = (t == 0) ? q_out : (t == 1) ? k_out : v_out;
                        dst[(((size_t)(bb * 16 + h)) * NTOK + nn) * 64 + d] =
                            f2b(acc[m][n][r]);
                    } else {
                        f_out[(size_t)gm * 1024 + gc] = acc[m][n][r] + bias[gc];
                    }
                }
            }
        }
    }
#undef STAGE_A
#undef STAGE_B
#undef LDA4
#undef LDB4
#undef MFMA16
#undef LGKM0_FENCE
}

// ---------- cls attention, split-K flash: part (1024 blocks) + fin (128 blocks) ----------
#define CSZ 393
__global__ __launch_bounds__(256) void attn_cls_part(const u16* __restrict__ qb,
                                                     const u16* __restrict__ kb,
                                                     const u16* __restrict__ vb,
                                                     float* __restrict__ part) {
    const int bid = blockIdx.x;
    const int bh = bid >> 3, c = bid & 7;
    const size_t base = (size_t)bh * NTOK * 64;
    const int tid = threadIdx.x, lane = tid & 63, wid = tid >> 6;
    const int j0 = c * CSZ;
    const int cnt = min(NTOK - j0, CSZ);

    __shared__ float qs[64];
    __shared__ float sc[CSZ];
    __shared__ float redbuf[8];
    __shared__ float ored[4][64];

    if (tid < 64) qs[tid] = b2f(qb[base + tid]);
    __syncthreads();

    for (int j = tid; j < cnt; j += 256) {
        const u16* kr = kb + base + (size_t)(j0 + j) * 64;
        float acc = 0.f;
#pragma unroll
        for (int c2 = 0; c2 < 8; ++c2) {
            short8 v8 = *(const short8*)(kr + c2 * 8);
#pragma unroll
            for (int t = 0; t < 8; ++t) acc += qs[c2 * 8 + t] * b2f((u16)v8[t]);
        }
        sc[j] = acc * 0.125f;
    }
    __syncthreads();

    float mx = -1e30f;
    for (int j = tid; j < cnt; j += 256) mx = fmaxf(mx, sc[j]);
#pragma unroll
    for (int m = 32; m >= 1; m >>= 1) mx = fmaxf(mx, __shfl_xor(mx, m));
    if (lane == 0) redbuf[wid] = mx;
    __syncthreads();
    mx = fmaxf(fmaxf(redbuf[0], redbuf[1]), fmaxf(redbuf[2], redbuf[3]));

    float sum = 0.f;
    for (int j = tid; j < cnt; j += 256) {
        float p = exp2f((sc[j] - mx) * LOG2E);
        sc[j] = p;
        sum += p;
    }
#pragma unroll
    for (int m = 32; m >= 1; m >>= 1) sum += __shfl_xor(sum, m);
    if (lane == 0) redbuf[4 + wid] = sum;
    __syncthreads();
    const float tot = redbuf[4] + redbuf[5] + redbuf[6] + redbuf[7];

    const int d = tid & 63, g = tid >> 6;
    float o = 0.f;
    for (int j = g; j < cnt; j += 4)
        o += sc[j] * b2f(vb[base + (size_t)(j0 + j) * 64 + d]);
    ored[g][d] = o;
    __syncthreads();

    float* pb = part + (size_t)bid * 66;
    if (tid < 64) pb[2 + tid] = ored[0][tid] + ored[1][tid] + ored[2][tid] + ored[3][tid];
    else if (tid == 64) pb[0] = mx;
    else if (tid == 65) pb[1] = tot;
}

__global__ __launch_bounds__(64) void attn_cls_fin(const float* __restrict__ part,
                                                   u16* __restrict__ attnb) {
    const int bh = blockIdx.x, d = threadIdx.x;
    const int bb = bh >> 4, h = bh & 15;
    float m = -1e30f;
#pragma unroll
    for (int c = 0; c < 8; ++c) m = fmaxf(m, part[(size_t)(bh * 8 + c) * 66]);
    float t = 0.f, o = 0.f;
#pragma unroll
    for (int c = 0; c < 8; ++c) {
        const float* pb = part + (size_t)(bh * 8 + c) * 66;
        const float w = exp2f((pb[0] - m) * LOG2E);
        t += w * pb[1];
        o += w * pb[2 + d];
    }
    attnb[(size_t)bb * NTOK * 1024 + h * 64 + d] = f2b(o / t);
}

// ---------- spatial attention: 2048 blocks, 79.7KB LDS -> 2 blocks/CU ----------
__global__ __launch_bounds__(256) void attn_spatial(const u16* __restrict__ qb,
                                                    const u16* __restrict__ kb,
                                                    const u16* __restrict__ vb,
                                                    u16* __restrict__ attnb) {
    const int blk = blockIdx.x;
    const int bh = blk >> 4, fi = blk & 15;
    const int bb = bh >> 4, h = bh & 15;
    const int tid = threadIdx.x, lane = tid & 63, wid = tid >> 6;
    const int hi = lane >> 4, lo = lane & 15;
    const size_t kvbase = (size_t)bh * NTOK * 64;

    __shared__ u16 Kl[197 * 72];
    __shared__ u16 Vt[64 * 208];
    __shared__ u16 Pl[4 * 16 * 208];

    u16* Ptmp = Pl;
    for (int idx = tid; idx < 197 * 8; idx += 256) {
        const int j = idx >> 3, c = idx & 7;
        const int n = (j == 0) ? 0 : (1 + fi * 196 + (j - 1));
        *(short8*)(Kl + j * 72 + c * 8) =
            *(const short8*)(kb + kvbase + (size_t)n * 64 + c * 8);
        *(short8*)(Ptmp + ((j * 64 + c * 8) ^ ((j & 7) << 3))) =
            *(const short8*)(vb + kvbase + (size_t)n * 64 + c * 8);
    }
    __syncthreads();
#pragma unroll
    for (int c = 0; c < 8; ++c) {
        if (tid < 197) {
            short8 v8 = *(const short8*)(Ptmp + ((tid * 64 + c * 8) ^ ((tid & 7) << 3)));
#pragma unroll
            for (int t = 0; t < 8; ++t) Vt[(c * 8 + t) * 208 + tid] = (u16)v8[t];
        }
    }
    for (int idx = tid; idx < 64 * 11; idx += 256)
        Vt[(idx / 11) * 208 + 197 + (idx % 11)] = 0;
    __syncthreads();

    u16* pl = Pl + wid * 16 * 208;
    const short8 z8 = {0, 0, 0, 0, 0, 0, 0, 0};
    const f32x4 zf = {0.f, 0.f, 0.f, 0.f};

    for (int mf = wid; mf < 13; mf += 4) {
        int qr = mf * 16 + lo; if (qr > 195) qr = 195;
        const u16* qp = qb + kvbase + (size_t)(1 + fi * 196 + qr) * 64 + hi * 8;
        const short8 a0 = *(const short8*)(qp);
        const short8 a1 = *(const short8*)(qp + 32);

        f32x4 s[13];
#pragma unroll
        for (int nf = 0; nf < 13; ++nf) s[nf] = zf;
#pragma unroll
        for (int nf = 0; nf < 13; ++nf) {
            int kr = nf * 16 + lo; if (kr > 196) kr = 196;
            const u16* kp = Kl + kr * 72 + hi * 8;
            const short8 b0 = *(const short8*)(kp);
            const short8 b1 = *(const short8*)(kp + 32);
            s[nf] = __builtin_amdgcn_mfma_f32_16x16x32_bf16(a0, b0, s[nf], 0, 0, 0);
            s[nf] = __builtin_amdgcn_mfma_f32_16x16x32_bf16(a1, b1, s[nf], 0, 0, 0);
        }

        float rls[4];
#pragma unroll
        for (int reg = 0; reg < 4; ++reg) {
            float mx = -1e30f;
#pragma unroll
            for (int nf = 0; nf < 13; ++nf) {
                const int col = nf * 16 + lo;
                float v = s[nf][reg] * 0.125f;
                if (col >= 197) v = -1e30f;
                s[nf][reg] = v;
                mx = fmaxf(mx, v);
            }
            mx = fmaxf(mx, __shfl_xor(mx, 1));
            mx = fmaxf(mx, __shfl_xor(mx, 2));
            mx = fmaxf(mx, __shfl_xor(mx, 4));
            mx = fmaxf(mx, __shfl_xor(mx, 8));
            float sum = 0.f;
#pragma unroll
            for (int nf = 0; nf < 13; ++nf) {
                const float p = exp2f((s[nf][reg] - mx) * LOG2E);
                s[nf][reg] = p;
                sum += p;
            }
            sum += __shfl_xor(sum, 1);
            sum += __shfl_xor(sum, 2);
            sum += __shfl_xor(sum, 4);
            sum += __shfl_xor(sum, 8);
            rls[reg] = 1.0f / sum;
        }

#pragma unroll
        for (int nf = 0; nf < 13; ++nf)
#pragma unroll
            for (int reg = 0; reg < 4; ++reg)
                pl[(hi * 4 + reg) * 208 + nf * 16 + lo] = f2b(s[nf][reg]);

        f32x4 o[4];
#pragma unroll
        for (int i = 0; i < 4; ++i) o[i] = zf;
#pragma unroll
        for (int kk = 0; kk < 6; ++kk) {
            const short8 pa = *(const short8*)(pl + lo * 208 + kk * 32 + hi * 8);
#pragma unroll
            for (int nf2 = 0; nf2 < 4; ++nf2) {
                const short8 bvv =
                    *(const short8*)(Vt + (nf2 * 16 + lo) * 208 + kk * 32 + hi * 8);
                o[nf2] = __builtin_amdgcn_mfma_f32_16x16x32_bf16(pa, bvv, o[nf2], 0, 0, 0);
            }
        }
        {
            const u16* pap = pl + lo * 208 + 192 + (hi < 2 ? hi * 8 : 0);
            short8 pa = *(const short8*)pap;
            if (hi >= 2) pa = z8;
#pragma unroll
            for (int nf2 = 0; nf2 < 4; ++nf2) {
                const u16* bvp = Vt + (nf2 * 16 + lo) * 208 + 192 + (hi < 2 ? hi * 8 : 0);
                short8 bvv = *(const short8*)bvp;
                if (hi >= 2) bvv = z8;
                o[nf2] = __builtin_amdgcn_mfma_f32_16x16x32_bf16(pa, bvv, o[nf2], 0, 0, 0);
            }
        }

#pragma unroll
        for (int nf2 = 0; nf2 < 4; ++nf2)
#pragma unroll
            for (int reg = 0; reg < 4; ++reg) {
                const int r = mf * 16 + hi * 4 + reg;
                if (r < 196) {
                    const int d = nf2 * 16 + lo;
                    const size_t nn = 1 + fi * 196 + r;
                    attnb[((size_t)bb * NTOK + nn) * 1024 + h * 64 + d] =
                        f2b(o[nf2][reg] * rls[reg]);
                }
            }
    }
}

// ---------- launch ----------
extern "C" void kernel_launch(void* const* d_in, const int* in_sizes, int n_in,
                              void* d_out, int out_size, void* d_ws, size_t ws_size,
                              hipStream_t stream) {
    const float* x = (const float*)d_in[0];
    const float* w_qkv = (const float*)d_in[1];
    const float* w_out = (const float*)d_in[2];
    const float* b_out = (const float*)d_in[3];

    const size_t need = ((size_t)QE * 2 + 3145728 + 1048576) * 2;
    if (ws_size < need) {
        hipMemsetAsync(d_out, 0, (size_t)out_size * 4, stream);
        return;
    }

    u16* vb = (u16*)d_ws;
    u16* xab = vb + QE;
    u16* wqb = xab + QE;
    u16* wob = wqb + 3145728;
    u16* qb = (u16*)d_out;
    u16* kb = qb + QE;
    float* outf = (float*)d_out;
    float* clsp = (float*)wqb;

    cvt_kernel<<<2048, 256, 0, stream>>>(x, xab, QE / 4);
    cvt_kernel<<<2048, 256, 0, stream>>>(w_qkv, wqb, 3145728 / 4);
    cvt_kernel<<<1024, 256, 0, stream>>>(w_out, wob, 1048576 / 4);

    gemm256<0><<<dim3(12, 99), 512, 0, stream>>>(xab, wqb, qb, kb, vb, nullptr,
                                                 nullptr, MROWS);
    attn_cls_part<<<1024, 256, 0, stream>>>(qb, kb, vb, clsp);
    attn_cls_fin<<<128, 64, 0, stream>>>(clsp, xab);
    attn_spatial<<<2048, 256, 0, stream>>>(qb, kb, vb, xab);
    gemm256<1><<<dim3(4, 99), 512, 0, stream>>>(xab, wob, nullptr, nullptr, nullptr,
                                                b_out, outf, MROWS);
}

// Round 4
// 465.151 us; speedup vs baseline: 1.9071x; 1.0104x over previous
//
#include <hip/hip_runtime.h>
#include <cstdint>
#include <cstddef>

#define DEVINL __device__ __forceinline__

typedef __attribute__((ext_vector_type(8))) short short8;
typedef __attribute__((ext_vector_type(4))) float f32x4;
typedef unsigned short u16;
typedef unsigned int u32;

// ---------- bf16 helpers (RNE) ----------
DEVINL u16 f2b(float f) {
    u32 u = __float_as_uint(f);
    u32 r = (u + 0x7fffu + ((u >> 16) & 1u)) >> 16;
    return (u16)r;
}
DEVINL float b2f(u16 h) { return __uint_as_float(((u32)h) << 16); }

DEVINL void gl_lds16(const void* g, void* l) {
    __builtin_amdgcn_global_load_lds(
        (const __attribute__((address_space(1))) void*)g,
        (__attribute__((address_space(3))) void*)l, 16, 0, 0);
}

// ---------- constants ----------
#define MROWS   25096
#define NTOK    3137
#define QE      25698304
#define LOG2E   1.4426950408889634f

// ---------- fp32 -> bf16 conversion ----------
__global__ __launch_bounds__(256) void cvt_kernel(const float* __restrict__ in,
                                                  u16* __restrict__ out, int n4) {
    int i = blockIdx.x * blockDim.x + threadIdx.x;
    int stride = gridDim.x * blockDim.x;
    for (int j = i; j < n4; j += stride) {
        float4 v = ((const float4*)in)[j];
        ushort4 o;
        o.x = f2b(v.x); o.y = f2b(v.y); o.z = f2b(v.z); o.w = f2b(v.w);
        ((ushort4*)out)[j] = o;
    }
}

// ================= 256x256 8-phase bf16 MFMA GEMM =================
// A row-major [M][1024], B = [N][1024] (B^T input). K = 1024, NT = 16 K-tiles.
// 512 threads = 8 waves (2 M x 4 N). LDS: 2 bufs x (A[2][256][32] + B[2][256][32]).
// T2 swizzle: within each 64-B row (4 x 16-B slots), phys_slot = log_slot ^ ((row>>1)&3).
//  - staging: LDS dest linear (gl_lds16), global SOURCE col pre-swizzled
//  - fragment reads use the same involution -> 8-lane beats hit all 32 banks once.
// Schedule per K-tile T (4 phases), counted vmcnt(4), never drains in main loop.

#define LDS_BUF 32768   // elems per buffer (A 16384 + B 16384)
#define NTILES  16

template <int MODE>
__global__ __launch_bounds__(512, 2) void gemm256(const u16* __restrict__ A,
                                                  const u16* __restrict__ B,
                                                  u16* __restrict__ q_out,
                                                  u16* __restrict__ k_out,
                                                  u16* __restrict__ v_out,
                                                  const float* __restrict__ bias,
                                                  float* __restrict__ f_out, int M) {
    __shared__ u16 lds[2 * LDS_BUF];   // 128 KiB
    const int tid = threadIdx.x, lane = tid & 63, w = tid >> 6;
    const int Mm1 = M - 1;

    // bijective XCD swizzle (m204)
    const u32 nwg = gridDim.x * gridDim.y;
    const u32 orig = blockIdx.y * gridDim.x + blockIdx.x;
    const u32 q8 = nwg >> 3, r8 = nwg & 7, xcd = orig & 7, rest = orig >> 3;
    const u32 wg = (xcd < r8 ? xcd * (q8 + 1) : r8 * (q8 + 1) + (xcd - r8) * q8) + rest;
    const int m0 = (int)(wg / gridDim.x) * 256;
    const int n0 = (int)(wg % gridDim.x) * 256;

    const int wm = w >> 2, wn = w & 3;

    // staging: chunk c = 2w+j covers 16 rows; lane -> dest row c*16 + (lane>>2),
    // dest phys slot (lane&3). Source col = (phys ^ f(row)) * 8, f(row) = (row>>1)&3.
    const int stRow = lane >> 2;
    const int stCol = (((lane & 3) ^ ((lane >> 3) & 3)) << 3);

    // fragment read offsets (elems): row*32 + (log_slot ^ f(row))*8 within [256][32] half
    const int slotOff = (((lane >> 4) ^ ((lane >> 1) & 3)) << 3);
    const int rdA = (wm * 128 + (lane & 15)) * 32 + slotOff;
    const int rdB = (wn * 64 + (lane & 15)) * 32 + slotOff + 16384;

#define STAGE_A(NB, KK, KT) do {                                              \
    _Pragma("unroll") for (int j_ = 0; j_ < 2; ++j_) {                        \
        const int c_ = (w << 1) | j_;                                         \
        int r_ = m0 + c_ * 16 + stRow; if (r_ > Mm1) r_ = Mm1;                \
        gl_lds16(A + (size_t)r_ * 1024 + (KT) + (KK) * 32 + stCol,            \
                 lds + (NB) + (KK) * 8192 + c_ * 512);                        \
    } } while (0)

#define STAGE_B(NB, KK, KT) do {                                              \
    _Pragma("unroll") for (int j_ = 0; j_ < 2; ++j_) {                        \
        const int c_ = (w << 1) | j_;                                         \
        const int r_ = n0 + c_ * 16 + stRow;                                  \
        gl_lds16(B + (size_t)r_ * 1024 + (KT) + (KK) * 32 + stCol,            \
                 lds + (NB) + 16384 + (KK) * 8192 + c_ * 512);                \
    } } while (0)

#define LDA4(CB, KK, MB) do {                                                 \
    _Pragma("unroll") for (int i_ = 0; i_ < 4; ++i_)                          \
        aF[i_] = *(const short8*)&lds[(CB) + (KK) * 8192 + rdA +              \
                                      ((MB) + i_) * 16 * 32];                 \
    } while (0)

#define LDB4(CB, KK) do {                                                     \
    _Pragma("unroll") for (int i_ = 0; i_ < 4; ++i_)                          \
        bF[i_] = *(const short8*)&lds[(CB) + (KK) * 8192 + rdB +              \
                                      i_ * 16 * 32];                          \
    } while (0)

#define MFMA16(MB) do {                                                       \
    _Pragma("unroll") for (int i_ = 0; i_ < 4; ++i_)                          \
        _Pragma("unroll") for (int n_ = 0; n_ < 4; ++n_)                      \
            acc[(MB) + i_][n_] = __builtin_amdgcn_mfma_f32_16x16x32_bf16(     \
                aF[i_], bF[n_], acc[(MB) + i_][n_], 0, 0, 0);                 \
    } while (0)

#define LGKM0_FENCE() do {                                                    \
    asm volatile("s_waitcnt lgkmcnt(0)" ::: "memory");                        \
    __builtin_amdgcn_sched_barrier(0); } while (0)

    f32x4 acc[8][4];
    const f32x4 zf = {0.f, 0.f, 0.f, 0.f};
#pragma unroll
    for (int i = 0; i < 8; ++i)
#pragma unroll
        for (int j = 0; j < 4; ++j) acc[i][j] = zf;

    // ---- prologue: stage tile 0 fully into buf0, prove k0 halves ----
    STAGE_A(0, 0, 0);
    STAGE_B(0, 0, 0);
    STAGE_A(0, 1, 0);
    STAGE_B(0, 1, 0);
    asm volatile("s_waitcnt vmcnt(4)" ::: "memory");
    __builtin_amdgcn_sched_barrier(0);
    __builtin_amdgcn_s_barrier();

    for (int T = 0; T < NTILES; ++T) {
        const int cb = (T & 1) * LDS_BUF;
        const int nb = ((T + 1) & 1) * LDS_BUF;
        const bool pf = (T < NTILES - 1);
        const int kt1 = (T + 1) * 64;

        short8 aF[4], bF[4];

        // ---- phase 1: kk0, m0-3 ----
        LDA4(cb, 0, 0);
        LDB4(cb, 0);
        if (pf) STAGE_A(nb, 0, kt1);
        __builtin_amdgcn_s_barrier();
        LGKM0_FENCE();
        __builtin_amdgcn_s_setprio(1);
        MFMA16(0);
        __builtin_amdgcn_s_setprio(0);
        __builtin_amdgcn_s_barrier();

        // ---- phase 2: kk0, m4-7 ----
        LDA4(cb, 0, 4);
        if (pf) STAGE_B(nb, 0, kt1);
        __builtin_amdgcn_s_barrier();
        LGKM0_FENCE();
        __builtin_amdgcn_s_setprio(1);
        MFMA16(4);
        __builtin_amdgcn_s_setprio(0);
        if (pf) { asm volatile("s_waitcnt vmcnt(4)" ::: "memory"); }
        else    { asm volatile("s_waitcnt vmcnt(0)" ::: "memory"); }
        __builtin_amdgcn_sched_barrier(0);
        __builtin_amdgcn_s_barrier();

        // ---- phase 3: kk1, m0-3 ----
        LDA4(cb, 1, 0);
        LDB4(cb, 1);
        if (pf) STAGE_A(nb, 1, kt1);
        __builtin_amdgcn_s_barrier();
        LGKM0_FENCE();
        __builtin_amdgcn_s_setprio(1);
        MFMA16(0);
        __builtin_amdgcn_s_setprio(0);
        __builtin_amdgcn_s_barrier();

        // ---- phase 4: kk1, m4-7 ----
        LDA4(cb, 1, 4);
        if (pf) STAGE_B(nb, 1, kt1);
        __builtin_amdgcn_s_barrier();
        LGKM0_FENCE();
        __builtin_amdgcn_s_setprio(1);
        MFMA16(4);
        __builtin_amdgcn_s_setprio(0);
        if (pf) {
            asm volatile("s_waitcnt vmcnt(4)" ::: "memory");
            __builtin_amdgcn_sched_barrier(0);
        }
        __builtin_amdgcn_s_barrier();
    }

    // ---- epilogue: C layout col=lane&15, row=(lane>>4)*4+reg ----
#pragma unroll
    for (int m = 0; m < 8; ++m) {
#pragma unroll
        for (int n = 0; n < 4; ++n) {
#pragma unroll
            for (int r = 0; r < 4; ++r) {
                const int gm = m0 + wm * 128 + m * 16 + ((lane >> 4) << 2) + r;
                if (gm < M) {
                    const int gc = n0 + wn * 64 + n * 16 + (lane & 15);
                    if (MODE == 0) {
                        const int t = gc >> 10;
                        const int h = (gc >> 6) & 15;
                        const int d = gc & 63;
                        const u32 bb = (u32)gm / 3137u;
                        const u32 nn = (u32)gm - bb * 3137u;
                        u16* dst = (t == 0) ? q_out : (t == 1) ? k_out : v_out;
                        dst[(((size_t)(bb * 16 + h)) * NTOK + nn) * 64 + d] =
                            f2b(acc[m][n][r]);
                    } else {
                        f_out[(size_t)gm * 1024 + gc] = acc[m][n][r] + bias[gc];
                    }
                }
            }
        }
    }
#undef STAGE_A
#undef STAGE_B
#undef LDA4
#undef LDB4
#undef MFMA16
#undef LGKM0_FENCE
}

// ---------- cls attention, split-K flash: part (1024 blocks) + fin (128 blocks) ----------
#define CSZ 393
__global__ __launch_bounds__(256) void attn_cls_part(const u16* __restrict__ qb,
                                                     const u16* __restrict__ kb,
                                                     const u16* __restrict__ vb,
                                                     float* __restrict__ part) {
    const int bid = blockIdx.x;
    const int bh = bid >> 3, c = bid & 7;
    const size_t base = (size_t)bh * NTOK * 64;
    const int tid = threadIdx.x, lane = tid & 63, wid = tid >> 6;
    const int j0 = c * CSZ;
    const int cnt = min(NTOK - j0, CSZ);

    __shared__ float qs[64];
    __shared__ float sc[CSZ];
    __shared__ float redbuf[8];
    __shared__ float ored[4][64];

    if (tid < 64) qs[tid] = b2f(qb[base + tid]);
    __syncthreads();

    for (int j = tid; j < cnt; j += 256) {
        const u16* kr = kb + base + (size_t)(j0 + j) * 64;
        float acc = 0.f;
#pragma unroll
        for (int c2 = 0; c2 < 8; ++c2) {
            short8 v8 = *(const short8*)(kr + c2 * 8);
#pragma unroll
            for (int t = 0; t < 8; ++t) acc += qs[c2 * 8 + t] * b2f((u16)v8[t]);
        }
        sc[j] = acc * 0.125f;
    }
    __syncthreads();

    float mx = -1e30f;
    for (int j = tid; j < cnt; j += 256) mx = fmaxf(mx, sc[j]);
#pragma unroll
    for (int m = 32; m >= 1; m >>= 1) mx = fmaxf(mx, __shfl_xor(mx, m));
    if (lane == 0) redbuf[wid] = mx;
    __syncthreads();
    mx = fmaxf(fmaxf(redbuf[0], redbuf[1]), fmaxf(redbuf[2], redbuf[3]));

    float sum = 0.f;
    for (int j = tid; j < cnt; j += 256) {
        float p = exp2f((sc[j] - mx) * LOG2E);
        sc[j] = p;
        sum += p;
    }
#pragma unroll
    for (int m = 32; m >= 1; m >>= 1) sum += __shfl_xor(sum, m);
    if (lane == 0) redbuf[4 + wid] = sum;
    __syncthreads();
    const float tot = redbuf[4] + redbuf[5] + redbuf[6] + redbuf[7];

    const int d = tid & 63, g = tid >> 6;
    float o = 0.f;
    for (int j = g; j < cnt; j += 4)
        o += sc[j] * b2f(vb[base + (size_t)(j0 + j) * 64 + d]);
    ored[g][d] = o;
    __syncthreads();

    float* pb = part + (size_t)bid * 66;
    if (tid < 64) pb[2 + tid] = ored[0][tid] + ored[1][tid] + ored[2][tid] + ored[3][tid];
    else if (tid == 64) pb[0] = mx;
    else if (tid == 65) pb[1] = tot;
}

__global__ __launch_bounds__(64) void attn_cls_fin(const float* __restrict__ part,
                                                   u16* __restrict__ attnb) {
    const int bh = blockIdx.x, d = threadIdx.x;
    const int bb = bh >> 4, h = bh & 15;
    float m = -1e30f;
#pragma unroll
    for (int c = 0; c < 8; ++c) m = fmaxf(m, part[(size_t)(bh * 8 + c) * 66]);
    float t = 0.f, o = 0.f;
#pragma unroll
    for (int c = 0; c < 8; ++c) {
        const float* pb = part + (size_t)(bh * 8 + c) * 66;
        const float w = exp2f((pb[0] - m) * LOG2E);
        t += w * pb[1];
        o += w * pb[2 + d];
    }
    attnb[(size_t)bb * NTOK * 1024 + h * 64 + d] = f2b(o / t);
}

// ---------- spatial attention: 2048 blocks, 79.7KB LDS -> 2 blocks/CU ----------
__global__ __launch_bounds__(256) void attn_spatial(const u16* __restrict__ qb,
                                                    const u16* __restrict__ kb,
                                                    const u16* __restrict__ vb,
                                                    u16* __restrict__ attnb) {
    const int blk = blockIdx.x;
    const int bh = blk >> 4, fi = blk & 15;
    const int bb = bh >> 4, h = bh & 15;
    const int tid = threadIdx.x, lane = tid & 63, wid = tid >> 6;
    const int hi = lane >> 4, lo = lane & 15;
    const size_t kvbase = (size_t)bh * NTOK * 64;

    __shared__ u16 Kl[197 * 72];
    __shared__ u16 Vt[64 * 208];
    __shared__ u16 Pl[4 * 16 * 208];

    u16* Ptmp = Pl;
    for (int idx = tid; idx < 197 * 8; idx += 256) {
        const int j = idx >> 3, c = idx & 7;
        const int n = (j == 0) ? 0 : (1 + fi * 196 + (j - 1));
        *(short8*)(Kl + j * 72 + c * 8) =
            *(const short8*)(kb + kvbase + (size_t)n * 64 + c * 8);
        *(short8*)(Ptmp + ((j * 64 + c * 8) ^ ((j & 7) << 3))) =
            *(const short8*)(vb + kvbase + (size_t)n * 64 + c * 8);
    }
    __syncthreads();
#pragma unroll
    for (int c = 0; c < 8; ++c) {
        if (tid < 197) {
            short8 v8 = *(const short8*)(Ptmp + ((tid * 64 + c * 8) ^ ((tid & 7) << 3)));
#pragma unroll
            for (int t = 0; t < 8; ++t) Vt[(c * 8 + t) * 208 + tid] = (u16)v8[t];
        }
    }
    for (int idx = tid; idx < 64 * 11; idx += 256)
        Vt[(idx / 11) * 208 + 197 + (idx % 11)] = 0;
    __syncthreads();

    u16* pl = Pl + wid * 16 * 208;
    const short8 z8 = {0, 0, 0, 0, 0, 0, 0, 0};
    const f32x4 zf = {0.f, 0.f, 0.f, 0.f};

    for (int mf = wid; mf < 13; mf += 4) {
        int qr = mf * 16 + lo; if (qr > 195) qr = 195;
        const u16* qp = qb + kvbase + (size_t)(1 + fi * 196 + qr) * 64 + hi * 8;
        const short8 a0 = *(const short8*)(qp);
        const short8 a1 = *(const short8*)(qp + 32);

        f32x4 s[13];
#pragma unroll
        for (int nf = 0; nf < 13; ++nf) s[nf] = zf;
#pragma unroll
        for (int nf = 0; nf < 13; ++nf) {
            int kr = nf * 16 + lo; if (kr > 196) kr = 196;
            const u16* kp = Kl + kr * 72 + hi * 8;
            const short8 b0 = *(const short8*)(kp);
            const short8 b1 = *(const short8*)(kp + 32);
            s[nf] = __builtin_amdgcn_mfma_f32_16x16x32_bf16(a0, b0, s[nf], 0, 0, 0);
            s[nf] = __builtin_amdgcn_mfma_f32_16x16x32_bf16(a1, b1, s[nf], 0, 0, 0);
        }

        float rls[4];
#pragma unroll
        for (int reg = 0; reg < 4; ++reg) {
            float mx = -1e30f;
#pragma unroll
            for (int nf = 0; nf < 13; ++nf) {
                const int col = nf * 16 + lo;
                float v = s[nf][reg] * 0.125f;
                if (col >= 197) v = -1e30f;
                s[nf][reg] = v;
                mx = fmaxf(mx, v);
            }
            mx = fmaxf(mx, __shfl_xor(mx, 1));
            mx = fmaxf(mx, __shfl_xor(mx, 2));
            mx = fmaxf(mx, __shfl_xor(mx, 4));
            mx = fmaxf(mx, __shfl_xor(mx, 8));
            float sum = 0.f;
#pragma unroll
            for (int nf = 0; nf < 13; ++nf) {
                const float p = exp2f((s[nf][reg] - mx) * LOG2E);
                s[nf][reg] = p;
                sum += p;
            }
            sum += __shfl_xor(sum, 1);
            sum += __shfl_xor(sum, 2);
            sum += __shfl_xor(sum, 4);
            sum += __shfl_xor(sum, 8);
            rls[reg] = 1.0f / sum;
        }

#pragma unroll
        for (int nf = 0; nf < 13; ++nf)
#pragma unroll
            for (int reg = 0; reg < 4; ++reg)
                pl[(hi * 4 + reg) * 208 + nf * 16 + lo] = f2b(s[nf][reg]);

        f32x4 o[4];
#pragma unroll
        for (int i = 0; i < 4; ++i) o[i] = zf;
#pragma unroll
        for (int kk = 0; kk < 6; ++kk) {
            const short8 pa = *(const short8*)(pl + lo * 208 + kk * 32 + hi * 8);
#pragma unroll
            for (int nf2 = 0; nf2 < 4; ++nf2) {
                const short8 bvv =
                    *(const short8*)(Vt + (nf2 * 16 + lo) * 208 + kk * 32 + hi * 8);
                o[nf2] = __builtin_amdgcn_mfma_f32_16x16x32_bf16(pa, bvv, o[nf2], 0, 0, 0);
            }
        }
        {
            const u16* pap = pl + lo * 208 + 192 + (hi < 2 ? hi * 8 : 0);
            short8 pa = *(const short8*)pap;
            if (hi >= 2) pa = z8;
#pragma unroll
            for (int nf2 = 0; nf2 < 4; ++nf2) {
                const u16* bvp = Vt + (nf2 * 16 + lo) * 208 + 192 + (hi < 2 ? hi * 8 : 0);
                short8 bvv = *(const short8*)bvp;
                if (hi >= 2) bvv = z8;
                o[nf2] = __builtin_amdgcn_mfma_f32_16x16x32_bf16(pa, bvv, o[nf2], 0, 0, 0);
            }
        }

#pragma unroll
        for (int nf2 = 0; nf2 < 4; ++nf2)
#pragma unroll
            for (int reg = 0; reg < 4; ++reg) {
                const int r = mf * 16 + hi * 4 + reg;
                if (r < 196) {
                    const int d = nf2 * 16 + lo;
                    const size_t nn = 1 + fi * 196 + r;
                    attnb[((size_t)bb * NTOK + nn) * 1024 + h * 64 + d] =
                        f2b(o[nf2][reg] * rls[reg]);
                }
            }
    }
}

// ---------- launch ----------
extern "C" void kernel_launch(void* const* d_in, const int* in_sizes, int n_in,
                              void* d_out, int out_size, void* d_ws, size_t ws_size,
                              hipStream_t stream) {
    const float* x = (const float*)d_in[0];
    const float* w_qkv = (const float*)d_in[1];
    const float* w_out = (const float*)d_in[2];
    const float* b_out = (const float*)d_in[3];

    const size_t need = ((size_t)QE * 2 + 3145728 + 1048576) * 2;
    if (ws_size < need) {
        hipMemsetAsync(d_out, 0, (size_t)out_size * 4, stream);
        return;
    }

    u16* vb = (u16*)d_ws;
    u16* xab = vb + QE;
    u16* wqb = xab + QE;
    u16* wob = wqb + 3145728;
    u16* qb = (u16*)d_out;
    u16* kb = qb + QE;
    float* outf = (float*)d_out;
    float* clsp = (float*)wqb;

    cvt_kernel<<<2048, 256, 0, stream>>>(x, xab, QE / 4);
    cvt_kernel<<<2048, 256, 0, stream>>>(w_qkv, wqb, 3145728 / 4);
    cvt_kernel<<<1024, 256, 0, stream>>>(w_out, wob, 1048576 / 4);

    gemm256<0><<<dim3(12, 99), 512, 0, stream>>>(xab, wqb, qb, kb, vb, nullptr,
                                                 nullptr, MROWS);
    attn_cls_part<<<1024, 256, 0, stream>>>(qb, kb, vb, clsp);
    attn_cls_fin<<<128, 64, 0, stream>>>(clsp, xab);
    attn_spatial<<<2048, 256, 0, stream>>>(qb, kb, vb, xab);
    gemm256<1><<<dim3(4, 99), 512, 0, stream>>>(xab, wob, nullptr, nullptr, nullptr,
                                                b_out, outf, MROWS);
}